// Round 1
// baseline (174.888 us; speedup 1.0000x reference)
//
#include <hip/hip_runtime.h>

#define MAXNB 64
#define CAP   128   // candidate capacity per query (expected ~35, max ~65)
#define PTILE 512   // points per scan tile

// ---------------------------------------------------------------------------
// Kernel 1: pack xyz -> float4 for both arrays, zero per-query hit counters.
// ---------------------------------------------------------------------------
__global__ __launch_bounds__(256) void pack_kernel(
    const float* __restrict__ inp, const float* __restrict__ qry,
    float4* __restrict__ ppack, float4* __restrict__ qpack,
    int* __restrict__ cnt, int n, int m) {
  int i = blockIdx.x * 256 + threadIdx.x;
  if (i < n) ppack[i] = make_float4(inp[3 * i], inp[3 * i + 1], inp[3 * i + 2], 0.f);
  if (i < m) {
    qpack[i] = make_float4(qry[3 * i], qry[3 * i + 1], qry[3 * i + 2], 0.f);
    cnt[i] = 0;
  }
}

// ---------------------------------------------------------------------------
// Kernel 2: brute-force scan. thread = query, blockIdx.y = point tile.
// Point load is block-uniform -> scalar (s_load) path; hits appended via
// atomicAdd into per-query candidate index list.
// ---------------------------------------------------------------------------
__global__ __launch_bounds__(256) void scan_kernel(
    const float4* __restrict__ pts, const float4* __restrict__ qrs,
    int* __restrict__ cnt, int* __restrict__ cidx) {
#pragma clang fp contract(off)
  const float R2 = (float)(0.08 * 0.08);
  int q = blockIdx.x * 256 + threadIdx.x;
  float4 Q = qrs[q];
  int p0 = blockIdx.y * PTILE;
  int p1 = p0 + PTILE;
#pragma unroll 4
  for (int j = p0; j < p1; ++j) {
    float4 P = pts[j];
    float dx = Q.x - P.x;
    float dy = Q.y - P.y;
    float dz = Q.z - P.z;
    float d2 = dx * dx + dy * dy + dz * dz;  // ((dx2+dy2)+dz2), contract OFF
    if (d2 <= R2) {
      int slot = atomicAdd(&cnt[q], 1);
      if (slot < CAP) cidx[q * CAP + slot] = j;
    }
  }
}

// ---------------------------------------------------------------------------
// Kernel 3: one wave per query (4 waves/block). Recompute d2 (bit-identical
// expression), rank candidates by (d2, idx) ascending, scatter idx to its
// rank slot, write 64 outputs (-1 padded) coalesced.
// ---------------------------------------------------------------------------
__global__ __launch_bounds__(256) void rank_kernel(
    const float4* __restrict__ pts, const float4* __restrict__ qrs,
    const int* __restrict__ cnt, const int* __restrict__ cidx,
    int* __restrict__ nbr) {
#pragma clang fp contract(off)
  __shared__ float sd2[4][CAP];
  __shared__ int sidx[4][CAP];
  __shared__ int souts[4][MAXNB];
  int w = threadIdx.x >> 6;
  int lane = threadIdx.x & 63;
  int q = blockIdx.x * 4 + w;
  float4 Q = qrs[q];
  int raw = cnt[q];
  int nc = raw < CAP ? raw : CAP;

  for (int c = lane; c < nc; c += 64) {
    int id = cidx[q * CAP + c];
    float4 P = pts[id];
    float dx = Q.x - P.x;
    float dy = Q.y - P.y;
    float dz = Q.z - P.z;
    sd2[w][c] = dx * dx + dy * dy + dz * dz;
    sidx[w][c] = id;
  }
  souts[w][lane] = -1;
  __syncthreads();

  for (int c = lane; c < nc; c += 64) {
    float myd = sd2[w][c];
    int myi = sidx[w][c];
    int rank = 0;
    for (int j = 0; j < nc; ++j) {
      float dj = sd2[w][j];
      int ij = sidx[w][j];
      rank += (dj < myd) || (dj == myd && ij < myi);
    }
    if (rank < MAXNB) souts[w][rank] = myi;
  }
  __syncthreads();

  nbr[(size_t)q * MAXNB + lane] = souts[w][lane];
}

// ---------------------------------------------------------------------------
// Kernel 4: row_splits = [0, cumsum(min(cnt,64))]. Single block, 256 threads,
// 64 counts per thread + Hillis-Steele scan over partials.
// ---------------------------------------------------------------------------
__global__ __launch_bounds__(256) void splits_kernel(
    const int* __restrict__ cnt, int* __restrict__ rs, int m) {
  __shared__ int part[256];
  int t = threadIdx.x;
  int per = m / 256;
  int base = t * per;
  int s = 0;
  for (int i = 0; i < per; ++i) {
    int c = cnt[base + i];
    if (c > MAXNB) c = MAXNB;
    s += c;
  }
  part[t] = s;
  __syncthreads();
  for (int off = 1; off < 256; off <<= 1) {
    int v = (t >= off) ? part[t - off] : 0;
    __syncthreads();
    part[t] += v;
    __syncthreads();
  }
  int run = (t == 0) ? 0 : part[t - 1];
  if (t == 0) rs[0] = 0;
  for (int i = 0; i < per; ++i) {
    int c = cnt[base + i];
    if (c > MAXNB) c = MAXNB;
    run += c;
    rs[base + i + 1] = run;
  }
}

// ---------------------------------------------------------------------------
extern "C" void kernel_launch(void* const* d_in, const int* in_sizes, int n_in,
                              void* d_out, int out_size, void* d_ws, size_t ws_size,
                              hipStream_t stream) {
  const float* inp = (const float*)d_in[0];  // inp_positions [N,3]
  const float* qry = (const float*)d_in[1];  // out_positions [M,3]
  int n = in_sizes[0] / 3;
  int m = in_sizes[1] / 3;

  char* ws = (char*)d_ws;
  float4* ppack = (float4*)ws;                           // n * 16 B
  float4* qpack = (float4*)(ws + (size_t)n * 16);        // m * 16 B
  int* cnt = (int*)(ws + (size_t)(n + m) * 16);          // m * 4 B
  int* cidx = (int*)(ws + (size_t)(n + m) * 16 + (size_t)m * 4);  // m*CAP*4 B

  int* nbr = (int*)d_out;                 // [m, 64]
  int* rs = nbr + (size_t)m * MAXNB;      // [m+1]

  int mx = n > m ? n : m;
  hipLaunchKernelGGL(pack_kernel, dim3((mx + 255) / 256), dim3(256), 0, stream,
                     inp, qry, ppack, qpack, cnt, n, m);
  hipLaunchKernelGGL(scan_kernel, dim3(m / 256, n / PTILE), dim3(256), 0, stream,
                     ppack, qpack, cnt, cidx);
  hipLaunchKernelGGL(rank_kernel, dim3(m / 4), dim3(256), 0, stream,
                     ppack, qpack, cnt, cidx, nbr);
  hipLaunchKernelGGL(splits_kernel, dim3(1), dim3(256), 0, stream, cnt, rs, m);
}